// Round 1
// baseline (782.747 us; speedup 1.0000x reference)
//
#include <hip/hip_runtime.h>
#include <hip/hip_bf16.h>
#include <cstdint>

#define B_N 64
#define C_N 2048
#define HW_N 196
#define M_N 32
#define NC_N 396
#define K_N 65536   // M_N * C_N

// ---------------------------------------------------------------------------
// K1: zpart[half][b][m][hw] = sum_{c in half} x[b][c][hw] * Wa[m][c]
// grid (4 hw-tiles, 64 b, 2 c-halves), block 256.
// Per-thread: 1 hw x 8 m, c-granule(4) inner -> 1 ds_read_b128 per 32 FMA.
// Wa rows read via wave-uniform scalar loads (readfirstlane on m-group).
// ---------------------------------------------------------------------------
__global__ __launch_bounds__(256) void k1_attn_part(
    const float* __restrict__ x, const float* __restrict__ Wa,
    float* __restrict__ zpart) {
  __shared__ float4 xs4[64][16];     // [hw][c-granule], XOR-swizzled
  const int t   = threadIdx.x;
  const int hw  = t & 63;
  const int mg  = t >> 6;            // 0..3
  const int b   = blockIdx.y;
  const int hw0 = blockIdx.x * 64;
  const int cbase = blockIdx.z * 1024;

  const int m0 = __builtin_amdgcn_readfirstlane(mg * 8);
  const float* __restrict__ wr[8];
#pragma unroll
  for (int j = 0; j < 8; ++j) wr[j] = Wa + (size_t)(m0 + j) * C_N + cbase;

  const float* __restrict__ xb = x + (size_t)b * C_N * HW_N;
  float acc[8];
#pragma unroll
  for (int j = 0; j < 8; ++j) acc[j] = 0.f;

  float* xsf = (float*)xs4;

  for (int cc0 = 0; cc0 < 1024; cc0 += 64) {
    __syncthreads();
    // stage 64c x 64hw tile, transposed (hw-major) + swizzled, zero-filled
#pragma unroll
    for (int i = 0; i < 4; ++i) {
      int lin = t + i * 256;           // 0..1023
      int hg  = lin & 15;              // hw-granule
      int cc  = lin >> 4;              // 0..63
      int h   = hw0 + hg * 4;
      float4 v = make_float4(0.f, 0.f, 0.f, 0.f);
      if (h + 3 < HW_N) {
        v = *(const float4*)(xb + (size_t)(cbase + cc0 + cc) * HW_N + h);
      } else if (h < HW_N) {
        const float* p = xb + (size_t)(cbase + cc0 + cc) * HW_N + h;
        float tmp[4] = {0.f, 0.f, 0.f, 0.f};
        for (int r = 0; r < HW_N - h; ++r) tmp[r] = p[r];
        v = make_float4(tmp[0], tmp[1], tmp[2], tmp[3]);
      }
      int gsw = cc >> 2;
#pragma unroll
      for (int r = 0; r < 4; ++r) {
        int row = hg * 4 + r;
        float val = (r == 0) ? v.x : (r == 1) ? v.y : (r == 2) ? v.z : v.w;
        xsf[row * 64 + (((gsw ^ (row & 15)) << 2) | (cc & 3))] = val;
      }
    }
    __syncthreads();
#pragma unroll 4
    for (int g = 0; g < 16; ++g) {
      float4 fv = xs4[hw][g ^ (hw & 15)];
      const int c = cc0 + g * 4;
#pragma unroll
      for (int j = 0; j < 8; ++j) {
        float4 wv = *(const float4*)(wr[j] + c);
        acc[j] = fmaf(fv.x, wv.x, acc[j]);
        acc[j] = fmaf(fv.y, wv.y, acc[j]);
        acc[j] = fmaf(fv.z, wv.z, acc[j]);
        acc[j] = fmaf(fv.w, wv.w, acc[j]);
      }
    }
  }
  if (hw0 + hw < HW_N) {
#pragma unroll
    for (int j = 0; j < 8; ++j) {
      zpart[(((size_t)blockIdx.z * B_N + b) * M_N + (m0 + j)) * HW_N + hw0 + hw] =
          acc[j];
    }
  }
}

// ---------------------------------------------------------------------------
// K1b: A = sigmoid(zpart[0] + zpart[1] + ba)
// ---------------------------------------------------------------------------
__global__ __launch_bounds__(256) void k1b_sigmoid(
    const float* __restrict__ zpart, const float* __restrict__ ba,
    float* __restrict__ A) {
  const int TOT = B_N * M_N * HW_N;
  int idx = blockIdx.x * 256 + threadIdx.x;
  if (idx >= TOT) return;
  int m = (idx / HW_N) & (M_N - 1);
  float z = zpart[idx] + zpart[TOT + idx] + ba[m];
  A[idx] = 1.f / (1.f + __expf(-z));
}

// ---------------------------------------------------------------------------
// K2: feats[b][m*C + c] = (1/196) * sum_hw x[b][c][hw] * A[b][m][hw]
// grid (8 c-tiles of 256, 64 b), block 256.
// Per-thread: 4 c x 8 m; x tile transposed+swizzled in LDS (hh-major);
// A rows via wave-uniform scalar loads.
// ---------------------------------------------------------------------------
__global__ __launch_bounds__(256) void k2_bap(
    const float* __restrict__ x, const float* __restrict__ A,
    float* __restrict__ feats) {
  __shared__ float4 xs4[32][64];   // [hh][c-granule 64], swizzled (32 KB)
  const int t  = threadIdx.x;
  const int cg = t & 63;           // c granule for compute
  const int mg = t >> 6;
  const int b  = blockIdx.y;
  const int c0 = blockIdx.x * 256;
  const int m0 = __builtin_amdgcn_readfirstlane(mg * 8);
  const float* __restrict__ ar[8];
#pragma unroll
  for (int j = 0; j < 8; ++j)
    ar[j] = A + ((size_t)b * M_N + (m0 + j)) * HW_N;
  const float* __restrict__ xb =
      x + (size_t)b * C_N * HW_N + (size_t)c0 * HW_N;

  float acc[8][4];
#pragma unroll
  for (int j = 0; j < 8; ++j)
#pragma unroll
    for (int r = 0; r < 4; ++r) acc[j][r] = 0.f;

  float* xsf = (float*)xs4;

  for (int h0 = 0; h0 < HW_N; h0 += 32) {
    const int nh = (HW_N - h0 < 32) ? (HW_N - h0) : 32;
    __syncthreads();
    // stage 256 c x nh hw, transposed+swizzled
#pragma unroll
    for (int i = 0; i < 8; ++i) {
      int lin = t + i * 256;   // 0..2047
      int hg  = lin & 7;       // hw-granule within chunk
      int cc  = lin >> 3;      // 0..255
      int h   = h0 + hg * 4;
      if (h < HW_N) {          // h multiple of 4 and HW_N=196 -> full quad valid
        float4 v = *(const float4*)(xb + (size_t)cc * HW_N + h);
        int gsw = cc >> 2;
#pragma unroll
        for (int r = 0; r < 4; ++r) {
          int row = hg * 4 + r;
          float val = (r == 0) ? v.x : (r == 1) ? v.y : (r == 2) ? v.z : v.w;
          xsf[row * 256 + (((gsw ^ (row & 15)) << 2) | (cc & 3))] = val;
        }
      }
    }
    __syncthreads();
#pragma unroll 4
    for (int hh = 0; hh < nh; ++hh) {
      float4 fv = xs4[hh][cg ^ (hh & 15)];
#pragma unroll
      for (int j = 0; j < 8; ++j) {
        float a = ar[j][h0 + hh];
        acc[j][0] = fmaf(fv.x, a, acc[j][0]);
        acc[j][1] = fmaf(fv.y, a, acc[j][1]);
        acc[j][2] = fmaf(fv.z, a, acc[j][2]);
        acc[j][3] = fmaf(fv.w, a, acc[j][3]);
      }
    }
  }
  const float s = 1.f / (float)HW_N;
#pragma unroll
  for (int j = 0; j < 8; ++j) {
    float4 o = make_float4(acc[j][0] * s, acc[j][1] * s,
                           acc[j][2] * s, acc[j][3] * s);
    *(float4*)(feats + (size_t)b * K_N + (size_t)(m0 + j) * C_N + c0 + cg * 4) = o;
  }
}

// ---------------------------------------------------------------------------
// K3: partial[kc][b*396+n] = sum_{k in chunk} feats[b][k] * Wc[n][k]
// grid (13 n-tiles of 32, 64 k-chunks of 1024), block 256, lane = b.
// Wc rows via wave-uniform scalar loads (the 104 MB HBM stream).
// ---------------------------------------------------------------------------
#define KC3 1024
__global__ __launch_bounds__(256) void k3_cls_part(
    const float* __restrict__ feats, const float* __restrict__ Wc,
    float* __restrict__ partial) {
  __shared__ float4 fs4[64][16];   // [b][k-granule], swizzled
  const int t  = threadIdx.x;
  const int bl = t & 63;
  const int ng = t >> 6;
  const size_t k0 = (size_t)blockIdx.y * KC3;
  const int n0 = __builtin_amdgcn_readfirstlane(blockIdx.x * 32 + ng * 8);
  const float* __restrict__ wrow[8];
#pragma unroll
  for (int j = 0; j < 8; ++j) {
    int n = n0 + j;
    wrow[j] = Wc + (size_t)(n < NC_N ? n : 0) * K_N + k0;
  }
  float acc[8];
#pragma unroll
  for (int j = 0; j < 8; ++j) acc[j] = 0.f;

  for (int ks = 0; ks < KC3; ks += 64) {
    __syncthreads();
#pragma unroll
    for (int i = 0; i < 4; ++i) {
      int lin = t + i * 256;      // 0..1023
      int g  = lin & 15;
      int bb = lin >> 4;          // 0..63
      fs4[bb][g ^ (bb & 15)] =
          *(const float4*)(feats + (size_t)bb * K_N + k0 + ks + g * 4);
    }
    __syncthreads();
#pragma unroll 4
    for (int g = 0; g < 16; ++g) {
      float4 fv = fs4[bl][g ^ (bl & 15)];
#pragma unroll
      for (int j = 0; j < 8; ++j) {
        float4 wv = *(const float4*)(wrow[j] + ks + g * 4);
        acc[j] = fmaf(fv.x, wv.x, acc[j]);
        acc[j] = fmaf(fv.y, wv.y, acc[j]);
        acc[j] = fmaf(fv.z, wv.z, acc[j]);
        acc[j] = fmaf(fv.w, wv.w, acc[j]);
      }
    }
  }
  float* po = partial + (size_t)blockIdx.y * (B_N * NC_N) + (size_t)bl * NC_N;
#pragma unroll
  for (int j = 0; j < 8; ++j) {
    int n = n0 + j;
    if (n < NC_N) po[n] = acc[j];
  }
}

// ---------------------------------------------------------------------------
// K4: out[b][n] = bc[n] + sum_kc partial[kc][b*396+n]
// ---------------------------------------------------------------------------
__global__ __launch_bounds__(256) void k4_reduce(
    const float* __restrict__ partial, const float* __restrict__ bc,
    float* __restrict__ out) {
  int idx = blockIdx.x * 256 + threadIdx.x;  // 25344 total
  if (idx >= B_N * NC_N) return;
  int n = idx % NC_N;
  float s = bc[n];
#pragma unroll 8
  for (int kc = 0; kc < 64; ++kc) s += partial[kc * (B_N * NC_N) + idx];
  out[idx] = s;
}

// ---------------------------------------------------------------------------
extern "C" void kernel_launch(void* const* d_in, const int* in_sizes, int n_in,
                              void* d_out, int out_size, void* d_ws, size_t ws_size,
                              hipStream_t stream) {
  const float* x  = (const float*)d_in[0];
  const float* Wa = (const float*)d_in[1];
  const float* ba = (const float*)d_in[2];
  const float* Wc = (const float*)d_in[3];
  const float* bc = (const float*)d_in[4];
  float* out = (float*)d_out;

  char* ws = (char*)d_ws;
  float* zpart   = (float*)(ws);                 // 2*64*32*196*4  = 3.21 MB
  float* A       = (float*)(ws + (4u  << 20));   // 64*32*196*4    = 1.61 MB
  float* feats   = (float*)(ws + (8u  << 20));   // 64*65536*4     = 16.8 MB
  float* partial = (float*)(ws + (26u << 20));   // 64*25344*4     = 6.49 MB
  (void)ws_size; (void)in_sizes; (void)n_in; (void)out_size;

  hipLaunchKernelGGL(k1_attn_part, dim3(4, 64, 2), dim3(256), 0, stream,
                     x, Wa, zpart);
  hipLaunchKernelGGL(k1b_sigmoid, dim3((B_N * M_N * HW_N + 255) / 256),
                     dim3(256), 0, stream, zpart, ba, A);
  hipLaunchKernelGGL(k2_bap, dim3(8, 64), dim3(256), 0, stream, x, A, feats);
  hipLaunchKernelGGL(k3_cls_part, dim3(13, 64), dim3(256), 0, stream,
                     feats, Wc, partial);
  hipLaunchKernelGGL(k4_reduce, dim3(99), dim3(256), 0, stream,
                     partial, bc, out);
}

// Round 2
// 358.779 us; speedup vs baseline: 2.1817x; 2.1817x over previous
//
#include <hip/hip_runtime.h>
#include <hip/hip_bf16.h>
#include <cstdint>

#define B_N 64
#define C_N 2048
#define HW_N 196
#define M_N 32
#define NC_N 396
#define K_N 65536   // M_N * C_N

// ---------------------------------------------------------------------------
// K1: zpart[q][b][m][hw] = sum_{c in chunk q} x[b][c][hw] * Wa[m][c]
// grid (2 hw-tiles of 128, 64 b, 4 c-chunks of 512), block 256.
// Thread: 2 hw x 8 m. x tile transposed+swizzled in LDS; Wa tile in LDS,
// read via wave-uniform broadcast (NOT s_load — round-1 latency trap).
// ---------------------------------------------------------------------------
__global__ __launch_bounds__(256) void k1_attn_part(
    const float* __restrict__ x, const float* __restrict__ Wa,
    float* __restrict__ zpart) {
  __shared__ float4 xs4[128][16];   // [hw-local][c-quad], XOR swizzled (32 KB)
  __shared__ float4 wl4[64][8];     // [c-local][m-quad] (8 KB)
  const int t  = threadIdx.x;
  const int l  = t & 63;
  const int w  = t >> 6;
  const int b  = blockIdx.y;
  const int hw0 = blockIdx.x * 128;
  const int cb  = blockIdx.z * 512;
  const float* __restrict__ xb = x + (size_t)b * (C_N * HW_N);

  float accA[8], accB[8];
#pragma unroll
  for (int j = 0; j < 8; ++j) { accA[j] = 0.f; accB[j] = 0.f; }

  float* xsf = (float*)xs4;
  float* wlf = (float*)wl4;

  for (int ct = 0; ct < 512; ct += 64) {
    __syncthreads();
    // stage x: 128 hw x 64 c, transposed (hw-major), granule-XOR swizzle
#pragma unroll
    for (int i = 0; i < 8; ++i) {
      int lin = t + i * 256;          // 0..2047
      int hg  = lin & 31;             // hw-quad
      int cc  = lin >> 5;             // 0..63
      int h   = hw0 + hg * 4;
      float4 v = make_float4(0.f, 0.f, 0.f, 0.f);
      if (h < HW_N)                   // HW_N=196: quads at mult-of-4 are full
        v = *(const float4*)(xb + (size_t)(cb + ct + cc) * HW_N + h);
      int g = cc >> 2, sub = cc & 3;
#pragma unroll
      for (int r = 0; r < 4; ++r) {
        int row = hg * 4 + r;
        xsf[row * 64 + (((g ^ (row & 15)) << 2) | sub)] = ((const float*)&v)[r];
      }
    }
    // stage Wa: 64 c x 32 m into [c][m]
#pragma unroll
    for (int i = 0; i < 2; ++i) {
      int lin = t + i * 256;          // 0..511
      int cq4 = lin & 15;
      int m   = lin >> 4;
      float4 v = *(const float4*)(Wa + (size_t)m * C_N + cb + ct + cq4 * 4);
#pragma unroll
      for (int r = 0; r < 4; ++r)
        wlf[(cq4 * 4 + r) * 32 + m] = ((const float*)&v)[r];
    }
    __syncthreads();
#pragma unroll 4
    for (int cq = 0; cq < 16; ++cq) {
      float4 fvA = xs4[l][cq ^ (l & 15)];
      float4 fvB = xs4[64 + l][cq ^ (l & 15)];
#pragma unroll
      for (int r = 0; r < 4; ++r) {
        float4 w0 = wl4[cq * 4 + r][w * 2 + 0];   // m = 8w..8w+3 (broadcast)
        float4 w1 = wl4[cq * 4 + r][w * 2 + 1];   // m = 8w+4..8w+7
        float fa = ((const float*)&fvA)[r];
        float fb = ((const float*)&fvB)[r];
        accA[0] = fmaf(fa, w0.x, accA[0]); accA[1] = fmaf(fa, w0.y, accA[1]);
        accA[2] = fmaf(fa, w0.z, accA[2]); accA[3] = fmaf(fa, w0.w, accA[3]);
        accA[4] = fmaf(fa, w1.x, accA[4]); accA[5] = fmaf(fa, w1.y, accA[5]);
        accA[6] = fmaf(fa, w1.z, accA[6]); accA[7] = fmaf(fa, w1.w, accA[7]);
        accB[0] = fmaf(fb, w0.x, accB[0]); accB[1] = fmaf(fb, w0.y, accB[1]);
        accB[2] = fmaf(fb, w0.z, accB[2]); accB[3] = fmaf(fb, w0.w, accB[3]);
        accB[4] = fmaf(fb, w1.x, accB[4]); accB[5] = fmaf(fb, w1.y, accB[5]);
        accB[6] = fmaf(fb, w1.z, accB[6]); accB[7] = fmaf(fb, w1.w, accB[7]);
      }
    }
  }
  const int hwA = hw0 + l;
  const int hwB = hw0 + 64 + l;
  const size_t base = ((size_t)blockIdx.z * B_N + b) * M_N;
#pragma unroll
  for (int j = 0; j < 8; ++j) {
    int m = w * 8 + j;
    zpart[(base + m) * HW_N + hwA] = accA[j];
    if (hwB < HW_N) zpart[(base + m) * HW_N + hwB] = accB[j];
  }
}

// ---------------------------------------------------------------------------
// K1b: A = sigmoid(sum_q zpart[q] + ba)
// ---------------------------------------------------------------------------
__global__ __launch_bounds__(256) void k1b_sigmoid(
    const float* __restrict__ zpart, const float* __restrict__ ba,
    float* __restrict__ A) {
  const int TOT = B_N * M_N * HW_N;       // 401408
  int idx = blockIdx.x * 256 + threadIdx.x;
  if (idx >= TOT) return;
  int m = (idx / HW_N) & (M_N - 1);
  float z = zpart[idx] + zpart[TOT + idx] + zpart[2 * TOT + idx] +
            zpart[3 * TOT + idx] + ba[m];
  A[idx] = 1.f / (1.f + __expf(-z));
}

// ---------------------------------------------------------------------------
// K2: feats[b][m*C+c] = (1/196) * sum_hw x[b][c][hw] * A[b][m][hw]
// grid (8 c-tiles of 256, 64 b), block 256. Thread: 4 c x 8 m.
// A[b] (25 KB) resident in LDS whole-block, flat copy; broadcast b32 reads.
// ---------------------------------------------------------------------------
__global__ __launch_bounds__(256) void k2_bap(
    const float* __restrict__ x, const float* __restrict__ A,
    float* __restrict__ feats) {
  __shared__ float4 atf4[1568];    // A[b] flat [m][hw] copy (25 KB)
  __shared__ float4 xs4[32][64];   // [hh][c-granule], swizzled (32 KB)
  const int t  = threadIdx.x;
  const int cg = t & 63;
  const int m0 = (t >> 6) * 8;
  const int b  = blockIdx.y;
  const int c0 = blockIdx.x * 256;
  const float* __restrict__ xb =
      x + (size_t)b * (C_N * HW_N) + (size_t)c0 * HW_N;

  // stage A[b] (coalesced, straight copy; barrier below covers first use)
  const float4* __restrict__ A4 = (const float4*)A + (size_t)b * 1568;
#pragma unroll
  for (int i = 0; i < 7; ++i) {
    int lin = t + i * 256;
    if (lin < 1568) atf4[lin] = A4[lin];
  }
  const float* atf = (const float*)atf4;

  float acc[8][4];
#pragma unroll
  for (int j = 0; j < 8; ++j)
#pragma unroll
    for (int r = 0; r < 4; ++r) acc[j][r] = 0.f;

  float* xsf = (float*)xs4;

  for (int h0 = 0; h0 < HW_N; h0 += 32) {
    const int nh = (HW_N - h0 < 32) ? (HW_N - h0) : 32;
    __syncthreads();
#pragma unroll
    for (int i = 0; i < 8; ++i) {
      int lin = t + i * 256;   // 0..2047
      int hg  = lin & 7;
      int cc  = lin >> 3;      // 0..255
      int h   = h0 + hg * 4;
      if (h < HW_N) {
        float4 v = *(const float4*)(xb + (size_t)cc * HW_N + h);
        int g = cc >> 2, sub = cc & 3;
#pragma unroll
        for (int r = 0; r < 4; ++r) {
          int row = hg * 4 + r;
          xsf[row * 256 + (((g ^ (row & 15)) << 2) | sub)] = ((const float*)&v)[r];
        }
      }
    }
    __syncthreads();
#pragma unroll 2
    for (int hh = 0; hh < nh; ++hh) {
      float4 fv = xs4[hh][cg ^ (hh & 15)];
      int h = h0 + hh;
#pragma unroll
      for (int j = 0; j < 8; ++j) {
        float a = atf[(m0 + j) * HW_N + h];   // wave-uniform -> LDS broadcast
        acc[j][0] = fmaf(fv.x, a, acc[j][0]);
        acc[j][1] = fmaf(fv.y, a, acc[j][1]);
        acc[j][2] = fmaf(fv.z, a, acc[j][2]);
        acc[j][3] = fmaf(fv.w, a, acc[j][3]);
      }
    }
  }
  const float s = 1.f / (float)HW_N;
#pragma unroll
  for (int j = 0; j < 8; ++j) {
    float4 o = make_float4(acc[j][0] * s, acc[j][1] * s,
                           acc[j][2] * s, acc[j][3] * s);
    *(float4*)(feats + (size_t)b * K_N + (size_t)(m0 + j) * C_N + c0 + cg * 4) = o;
  }
}

// ---------------------------------------------------------------------------
// K3: partial[kc][b][n] = sum_{k in chunk} feats[b][k] * Wc[n][k]
// grid (7 n-tiles of 64, 64 k-chunks of 1024), block 256.
// Block tile 64b x 64n; thread 4x4 with b/n strided by 16 (LDS reads:
// fs = 16 rows x 4-lane broadcast, 2-way banks; ws = 4-row broadcast).
// ---------------------------------------------------------------------------
__global__ __launch_bounds__(256) void k3_cls_part(
    const float* __restrict__ feats, const float* __restrict__ Wc,
    float* __restrict__ partial) {
  __shared__ float fs[64 * 68];   // feats tile [b][k], pad 68 (17.4 KB)
  __shared__ float ws[64 * 68];   // Wc tile [n-local][k], pad 68
  const int t  = threadIdx.x;
  const int bg = t & 15;          // b = bg + 16*i
  const int ng = t >> 4;          // n = n0 + ng + 16*j
  const int n0 = blockIdx.x * 64;
  const size_t k0 = (size_t)blockIdx.y * 1024;

  float acc[4][4];
#pragma unroll
  for (int i = 0; i < 4; ++i)
#pragma unroll
    for (int j = 0; j < 4; ++j) acc[i][j] = 0.f;

  for (int ks = 0; ks < 16; ++ks) {
    __syncthreads();
#pragma unroll
    for (int i = 0; i < 4; ++i) {
      int lin = t + i * 256;      // 0..1023
      int kg  = lin & 15;
      int row = lin >> 4;         // 0..63
      *(float4*)(fs + row * 68 + kg * 4) =
          *(const float4*)(feats + (size_t)row * K_N + k0 + ks * 64 + kg * 4);
      int n = n0 + row; if (n > NC_N - 1) n = NC_N - 1;
      *(float4*)(ws + row * 68 + kg * 4) =
          *(const float4*)(Wc + (size_t)n * K_N + k0 + ks * 64 + kg * 4);
    }
    __syncthreads();
#pragma unroll 4
    for (int kq = 0; kq < 16; ++kq) {
      float4 fq[4], wq[4];
#pragma unroll
      for (int i = 0; i < 4; ++i)
        fq[i] = *(const float4*)(fs + (bg + 16 * i) * 68 + kq * 4);
#pragma unroll
      for (int j = 0; j < 4; ++j)
        wq[j] = *(const float4*)(ws + (ng + 16 * j) * 68 + kq * 4);
#pragma unroll
      for (int i = 0; i < 4; ++i)
#pragma unroll
        for (int j = 0; j < 4; ++j) {
          acc[i][j] = fmaf(fq[i].x, wq[j].x, acc[i][j]);
          acc[i][j] = fmaf(fq[i].y, wq[j].y, acc[i][j]);
          acc[i][j] = fmaf(fq[i].z, wq[j].z, acc[i][j]);
          acc[i][j] = fmaf(fq[i].w, wq[j].w, acc[i][j]);
        }
    }
  }
  float* po = partial + (size_t)blockIdx.y * (B_N * NC_N);
#pragma unroll
  for (int i = 0; i < 4; ++i)
#pragma unroll
    for (int j = 0; j < 4; ++j) {
      int n = n0 + ng + 16 * j;
      if (n < NC_N) po[(bg + 16 * i) * NC_N + n] = acc[i][j];
    }
}

// ---------------------------------------------------------------------------
// K4: out[b][n] = bc[n] + sum_kc partial[kc][b][n]
// ---------------------------------------------------------------------------
__global__ __launch_bounds__(256) void k4_reduce(
    const float* __restrict__ partial, const float* __restrict__ bc,
    float* __restrict__ out) {
  int idx = blockIdx.x * 256 + threadIdx.x;  // 25344 total
  if (idx >= B_N * NC_N) return;
  int n = idx % NC_N;
  float s = bc[n];
#pragma unroll 8
  for (int kc = 0; kc < 64; ++kc) s += partial[kc * (B_N * NC_N) + idx];
  out[idx] = s;
}

// ---------------------------------------------------------------------------
extern "C" void kernel_launch(void* const* d_in, const int* in_sizes, int n_in,
                              void* d_out, int out_size, void* d_ws, size_t ws_size,
                              hipStream_t stream) {
  const float* x  = (const float*)d_in[0];
  const float* Wa = (const float*)d_in[1];
  const float* ba = (const float*)d_in[2];
  const float* Wc = (const float*)d_in[3];
  const float* bc = (const float*)d_in[4];
  float* out = (float*)d_out;

  char* ws = (char*)d_ws;
  // lifetimes: A [k1b..k2], zpart [k1..k1b], feats [k2..k3], partial [k3..k4]
  float* A       = (float*)(ws);                 // 1.61 MB
  float* zpart   = (float*)(ws + (2u  << 20));   // 4*64*32*196*4 = 6.42 MB
  float* feats   = (float*)(ws + (9u  << 20));   // 64*65536*4    = 16.8 MB
  float* partial = (float*)(ws + (26u << 20));   // 64*25344*4    = 6.49 MB
  (void)ws_size; (void)in_sizes; (void)n_in; (void)out_size;

  hipLaunchKernelGGL(k1_attn_part, dim3(2, 64, 4), dim3(256), 0, stream,
                     x, Wa, zpart);
  hipLaunchKernelGGL(k1b_sigmoid, dim3((B_N * M_N * HW_N + 255) / 256),
                     dim3(256), 0, stream, zpart, ba, A);
  hipLaunchKernelGGL(k2_bap, dim3(8, 64), dim3(256), 0, stream, x, A, feats);
  hipLaunchKernelGGL(k3_cls_part, dim3(7, 64), dim3(256), 0, stream,
                     feats, Wc, partial);
  hipLaunchKernelGGL(k4_reduce, dim3(99), dim3(256), 0, stream,
                     partial, bc, out);
}